// Round 2
// 2617.563 us; speedup vs baseline: 4.2608x; 4.2608x over previous
//
#include <hip/hip_runtime.h>
#include <hip/hip_bf16.h>

// B=4, C=128, G=64, K=3, SC=512, H_hf=256, H_lf=128
#define BB 4
#define CCH 128
#define GRP 64
#define SCH 512
#define EPSV 1e-5f

typedef unsigned short u16;

__device__ __forceinline__ float b2f(u16 u) {
    return __uint_as_float(((unsigned int)u) << 16);
}
__device__ __forceinline__ u16 f2b(float f) {
    unsigned int u = __float_as_uint(f);
    return (u16)((u + 0x7fffu + ((u >> 16) & 1u)) >> 16);
}
__device__ __forceinline__ int refl(int i, int n) {
    if (i < 0) i = -i;
    if (i >= n) i = 2 * n - 2 - i;
    return i;
}
// dtype-flagged load/store: isbf=1 -> bf16 array, else f32 array
__device__ __forceinline__ float ldv(const void* p, long long i, int isbf) {
    return isbf ? b2f(((const u16*)p)[i]) : ((const float*)p)[i];
}
__device__ __forceinline__ void stv(void* p, long long i, int isbf, float v) {
    if (isbf) ((u16*)p)[i] = f2b(v);
    else ((float*)p)[i] = v;
}

// ---------------------------------------------------------------------------
// D0: dtype detector. Sample even u16 words of c_hf. If data is bf16, even
// words are bf16 values of N(0,1) samples (~99% of |v| in [0.004,8]). If f32,
// even words are low mantissa bits (uniform) -> ~5% in range.
__global__ __launch_bounds__(256) void detect_kernel(const void* x, int* flag) {
    const u16* p = (const u16*)x;
    int tid = threadIdx.x;
    int cnt = 0;
#pragma unroll
    for (int k = 0; k < 16; ++k) {
        float v = fabsf(b2f(p[2 * (tid * 16 + k)]));
        if (v > 0.004f && v < 8.0f) cnt++;
    }
    __shared__ int red[256];
    red[tid] = cnt;
    __syncthreads();
    for (int st = 128; st > 0; st >>= 1) {
        if (tid < st) red[tid] += red[tid + st];
        __syncthreads();
    }
    if (tid == 0) flag[0] = (red[0] >= 2048) ? 1 : 0;
}

// ---------------------------------------------------------------------------
// K0: per-(b,k) mean of 3x3 style map -> sm [B,512]
__global__ __launch_bounds__(256) void sm_kernel(const int* flag, const void* s, float* sm) {
    int idx = blockIdx.x * 256 + threadIdx.x;
    if (idx >= BB * SCH) return;
    int isbf = flag[0];
    float t = 0.f;
#pragma unroll
    for (int j = 0; j < 9; ++j) t += ldv(s, (long long)idx * 9 + j, isbf);
    sm[idx] = t * (1.0f / 9.0f);
}

// ---------------------------------------------------------------------------
// K1: spatial predictor: reflect-pad 3x3 -> 5x5, conv [256,512,3,3] -> wsp [B,256,9]
__global__ __launch_bounds__(256) void spconv_kernel(const int* flag, const void* s,
                                                     const void* sp_w, const void* sp_b,
                                                     float* wsp_out) {
    int isbf = flag[0];
    int b = blockIdx.x >> 8;
    int oc = blockIdx.x & 255;
    int tid = threadIdx.x;
    float acc[9];
#pragma unroll
    for (int o = 0; o < 9; ++o) acc[o] = 0.f;
    for (int ic = tid; ic < SCH; ic += 256) {
        float sv[9], wv[9];
#pragma unroll
        for (int j = 0; j < 9; ++j) sv[j] = ldv(s, (long long)(b * SCH + ic) * 9 + j, isbf);
#pragma unroll
        for (int j = 0; j < 9; ++j) wv[j] = ldv(sp_w, (long long)(oc * SCH + ic) * 9 + j, isbf);
        const int m[5] = {1, 0, 1, 2, 1};
#pragma unroll
        for (int oy = 0; oy < 3; ++oy) {
#pragma unroll
            for (int ox = 0; ox < 3; ++ox) {
                float t = 0.f;
#pragma unroll
                for (int kr = 0; kr < 3; ++kr)
#pragma unroll
                    for (int kc = 0; kc < 3; ++kc)
                        t += sv[m[oy + kr] * 3 + m[ox + kc]] * wv[kr * 3 + kc];
                acc[oy * 3 + ox] += t;
            }
        }
    }
    __shared__ float red[256];
#pragma unroll 1
    for (int o = 0; o < 9; ++o) {
        red[tid] = acc[o];
        __syncthreads();
        for (int st = 128; st > 0; st >>= 1) {
            if (tid < st) red[tid] += red[tid + st];
            __syncthreads();
        }
        if (tid == 0) wsp_out[(b * 256 + oc) * 9 + o] = red[0] + ldv(sp_b, oc, isbf);
        __syncthreads();
    }
}

// ---------------------------------------------------------------------------
// K2: pointwise weights + bias predictor (GEMV over 512)
__global__ __launch_bounds__(256) void pwbias_kernel(const int* flag, const float* __restrict__ sm,
                                                     const void* pw_w, const void* pw_b,
                                                     const void* b_w, const void* b_b,
                                                     float* wpw, float* biasout) {
    int idx = blockIdx.x * 256 + threadIdx.x;
    if (idx >= BB * 384) return;
    int isbf = flag[0];
    int b = idx / 384;
    int j = idx % 384;
    const float* smb = sm + b * SCH;
    if (j < 256) {
        float a = 0.f;
        for (int k = 0; k < SCH; ++k) a += smb[k] * ldv(pw_w, (long long)j * SCH + k, isbf);
        wpw[b * 256 + j] = a + ldv(pw_b, j, isbf);
    } else {
        int j2 = j - 256;
        float a = 0.f;
        for (int k = 0; k < SCH; ++k) a += smb[k] * ldv(b_w, (long long)j2 * SCH + k, isbf);
        biasout[b * CCH + j2] = a + ldv(b_b, j2, isbf);
    }
}

// ---------------------------------------------------------------------------
// K3: per-(b,c) mean / rstd over HW. One block per (b,c).
__global__ __launch_bounds__(256) void stats_kernel(const int* flag, const void* x, long long off,
                                                    float* stat, int HW) {
    int isbf = flag[0];
    int bc = blockIdx.x;
    int tid = threadIdx.x;
    long long base = off + (long long)bc * HW;
    float s = 0.f, s2 = 0.f;
    for (int i = tid; i < HW; i += 256) {
        float v = ldv(x, base + i, isbf);
        s += v;
        s2 += v * v;
    }
    __shared__ float rs[256];
    __shared__ float rq[256];
    rs[tid] = s;
    rq[tid] = s2;
    __syncthreads();
    for (int st = 128; st > 0; st >>= 1) {
        if (tid < st) { rs[tid] += rs[tid + st]; rq[tid] += rq[tid + st]; }
        __syncthreads();
    }
    if (tid == 0) {
        float inv = 1.0f / (float)HW;
        float mean = rs[0] * inv;
        float var = rq[0] * inv - mean * mean;
        stat[bc * 2] = mean;
        stat[bc * 2 + 1] = rsqrtf(var + EPSV);
    }
}

// ---------------------------------------------------------------------------
// K4: banded fused inorm + grouped spatial + grouped pointwise.
// Computes y2 (f32) for band rows r0-1 .. r0+32 (reflected), 34 rows.
// band layout: [b*128+c][34][W] f32
__global__ __launch_bounds__(256) void grouped_band_kernel(const int* flag, const void* x,
                                                           const float* __restrict__ xstat,
                                                           const float* __restrict__ wsp,
                                                           const float* __restrict__ wpw,
                                                           const float* __restrict__ bias,
                                                           float* __restrict__ band,
                                                           int H, int W, int r0) {
    int isbf = flag[0];
    int ppb = (34 * W) >> 8;  // 256-pixel blocks per (b,g)
    int t = blockIdx.x;
    int bg = t / ppb;
    int tile = t - bg * ppb;
    int b = bg >> 6;
    int g = bg & 63;
    int tid = threadIdx.x;

    __shared__ float sw[36], pw[4], bs[2], xm[2], xr[2];
    if (tid < 36) {
        int o = tid / 18, i = (tid % 18) / 9, k = tid % 9;
        sw[tid] = wsp[(b * 256 + (2 * g + o) * 2 + i) * 9 + k];
    }
    if (tid < 4) pw[tid] = wpw[b * 256 + (2 * g + (tid >> 1)) * 2 + (tid & 1)];
    if (tid < 2) {
        bs[tid] = bias[b * CCH + 2 * g + tid];
        xm[tid] = xstat[(b * CCH + 2 * g + tid) * 2];
        xr[tid] = xstat[(b * CCH + 2 * g + tid) * 2 + 1];
    }
    __syncthreads();

    int p = tile * 256 + tid;
    int j = p / W;
    int col = p - j * W;
    int grow = refl(r0 - 1 + j, H);

    float y10 = 0.f, y11 = 0.f;
#pragma unroll
    for (int i = 0; i < 2; ++i) {
        long long xb = (long long)(b * CCH + 2 * g + i) * H * W;
        float m = xm[i], r = xr[i];
#pragma unroll
        for (int kr = 0; kr < 3; ++kr) {
            int rr = refl(grow + kr - 1, H) * W;
#pragma unroll
            for (int kc = 0; kc < 3; ++kc) {
                int cc = refl(col + kc - 1, W);
                float xv = (ldv(x, xb + rr + cc, isbf) - m) * r;
                y10 += xv * sw[i * 9 + kr * 3 + kc];
                y11 += xv * sw[18 + i * 9 + kr * 3 + kc];
            }
        }
    }
    band[((long long)(b * CCH + 2 * g) * 34 + j) * W + col] = pw[0] * y10 + pw[1] * y11 + bs[0];
    band[((long long)(b * CCH + 2 * g + 1) * 34 + j) * W + col] = pw[2] * y10 + pw[3] * y11 + bs[1];
}

// ---------------------------------------------------------------------------
// K5: LDS-staged register-tiled shared 3x3 conv 128->128 + bias.
// Block: 256 threads = 16x16 thread grid; thread computes 2 rows x 4 cols x 4 ocs.
// Tile: 32 rows x 64 cols x 4 ocs. Input band staged to LDS in chunks of 4 ics.
// LDS: weights 4oc*128ic*9 = 18.4KB + ins [4][34][68] = 37KB -> 55.4KB, 2 blocks/CU.
// nbands>1: multiple 32-row band regions resident (lf), bandstride floats apart.
__global__ __launch_bounds__(256, 2) void bigconv_tile_kernel(
    const int* flag, const float* __restrict__ band,
    const void* cw, const void* cb, void* out, long long ooff,
    int H, int W, int r0, int nbands, long long bandstride) {
    int isbf = flag[0];
    int ctiles = W >> 6;
    int per_band = BB * 32 * ctiles;
    int t = blockIdx.x;
    int bandidx = t / per_band;
    int rem = t - bandidx * per_band;
    int b = rem / (32 * ctiles);
    int rem2 = rem - b * (32 * ctiles);
    int ocb = rem2 / ctiles;
    int tx0 = (rem2 - ocb * ctiles) << 6;
    int rr0 = r0 + 32 * bandidx;
    const float* bandb = band + bandidx * bandstride + (long long)b * CCH * 34 * W;

    int tid = threadIdx.x;
    int tr = tid >> 4;   // 0..15 -> output rows rr0 + tr*2 + {0,1}
    int tc = tid & 15;   // 0..15 -> output cols tx0 + tc*4 + {0..3}

    __shared__ float wsh[4608];   // [ic][ol*9+k]
    __shared__ float ins[9248];   // [4][34][68]; col0 = halo-L, 1..64 body, 65 halo-R

    for (int idx = tid; idx < 4608; idx += 256) {
        int ic = idx / 36;
        int r = idx - ic * 36;
        int ol = r / 9;
        int k = r - ol * 9;
        wsh[idx] = ldv(cw, ((long long)(ocb * 4 + ol) * CCH + ic) * 9 + k, isbf);
    }

    float acc[32];  // [ol][py][px]
#pragma unroll
    for (int ol = 0; ol < 4; ++ol) {
        float bv = ldv(cb, ocb * 4 + ol, isbf);
#pragma unroll
        for (int p = 0; p < 8; ++p) acc[ol * 8 + p] = bv;
    }

    int gcl = refl(tx0 - 1, W);
    int gcr = refl(tx0 + 64, W);

#pragma unroll 1
    for (int icc = 0; icc < 32; ++icc) {
        // ---- stage loads (chunk icc: ics icc*4 .. icc*4+3) into registers
        float4 bodyv[9];
        float hv[2];
#pragma unroll
        for (int k = 0; k < 9; ++k) {
            int rowid = k * 16 + tr;  // 0..143; valid < 136 (= 4 ic * 34 rows)
            if (rowid < 136) {
                bodyv[k] = *reinterpret_cast<const float4*>(
                    bandb + (long long)(icc * 136 + rowid) * W + tx0 + tc * 4);
            }
        }
#pragma unroll
        for (int k = 0; k < 2; ++k) {
            int h = k * 256 + tid;  // 0..511; valid < 272 (= 136 rows * 2 sides)
            if (h < 272) {
                int rh = h >> 1;
                int side = h & 1;
                hv[k] = bandb[(long long)(icc * 136 + rh) * W + (side ? gcr : gcl)];
            }
        }
        __syncthreads();  // previous chunk fully consumed (also covers wsh init)
        // ---- LDS writes
#pragma unroll
        for (int k = 0; k < 9; ++k) {
            int rowid = k * 16 + tr;
            if (rowid < 136) {
                int icl = rowid / 34;
                int rr = rowid - icl * 34;
                float* d = &ins[icl * 2312 + rr * 68 + 1 + tc * 4];
                d[0] = bodyv[k].x; d[1] = bodyv[k].y; d[2] = bodyv[k].z; d[3] = bodyv[k].w;
            }
        }
#pragma unroll
        for (int k = 0; k < 2; ++k) {
            int h = k * 256 + tid;
            if (h < 272) {
                int rh = h >> 1;
                int side = h & 1;
                int icl = rh / 34;
                int rr = rh - icl * 34;
                ins[icl * 2312 + rr * 68 + (side ? 65 : 0)] = hv[k];
            }
        }
        __syncthreads();  // chunk ready

        // ---- compute 4 ics
#pragma unroll
        for (int icl = 0; icl < 4; ++icl) {
            float wr[36];
            const float* wp = &wsh[(icc * 4 + icl) * 36];
#pragma unroll
            for (int k = 0; k < 9; ++k) {  // wave-uniform broadcast reads
                float4 w4 = *reinterpret_cast<const float4*>(wp + 4 * k);
                wr[4 * k] = w4.x; wr[4 * k + 1] = w4.y;
                wr[4 * k + 2] = w4.z; wr[4 * k + 3] = w4.w;
            }
            float win[32];  // 4 rows x 8 cols (6 used)
            const float* ip = &ins[icl * 2312 + (tr * 2) * 68 + tc * 4];
#pragma unroll
            for (int jj = 0; jj < 4; ++jj) {
                float4 lo = *reinterpret_cast<const float4*>(ip + jj * 68);
                float4 hi = *reinterpret_cast<const float4*>(ip + jj * 68 + 4);
                win[jj * 8 + 0] = lo.x; win[jj * 8 + 1] = lo.y;
                win[jj * 8 + 2] = lo.z; win[jj * 8 + 3] = lo.w;
                win[jj * 8 + 4] = hi.x; win[jj * 8 + 5] = hi.y;
                win[jj * 8 + 6] = hi.z; win[jj * 8 + 7] = hi.w;
            }
#pragma unroll
            for (int ol = 0; ol < 4; ++ol)
#pragma unroll
                for (int py = 0; py < 2; ++py)
#pragma unroll
                    for (int px = 0; px < 4; ++px) {
                        float a = acc[ol * 8 + py * 4 + px];
#pragma unroll
                        for (int kr = 0; kr < 3; ++kr)
#pragma unroll
                            for (int kc = 0; kc < 3; ++kc)
                                a += win[(py + kr) * 8 + px + kc] * wr[ol * 9 + kr * 3 + kc];
                        acc[ol * 8 + py * 4 + px] = a;
                    }
        }
    }

#pragma unroll
    for (int ol = 0; ol < 4; ++ol) {
        long long oco = ooff + (long long)(b * CCH + ocb * 4 + ol) * H * W;
#pragma unroll
        for (int py = 0; py < 2; ++py) {
            long long rowo = oco + (long long)(rr0 + tr * 2 + py) * W + tx0 + tc * 4;
#pragma unroll
            for (int px = 0; px < 4; ++px)
                stv(out, rowo + px, isbf, acc[ol * 8 + py * 4 + px]);
        }
    }
}

// ---------------------------------------------------------------------------
// K6: final instance-norm + leaky relu, in place on d_out.
__global__ __launch_bounds__(256) void finalize_kernel(const int* flag, void* y, long long off,
                                                       const float* __restrict__ stat,
                                                       int HW, long long total) {
    long long idx = (long long)blockIdx.x * 256 + threadIdx.x;
    if (idx >= total) return;
    int isbf = flag[0];
    int bc = (int)(idx / HW);
    float m = stat[bc * 2];
    float r = stat[bc * 2 + 1];
    float v = (ldv(y, off + idx, isbf) - m) * r;
    stv(y, off + idx, isbf, v >= 0.f ? v : 0.2f * v);
}

// ---------------------------------------------------------------------------
extern "C" void kernel_launch(void* const* d_in, const int* in_sizes, int n_in,
                              void* d_out, int out_size, void* d_ws, size_t ws_size,
                              hipStream_t stream) {
    const void* c_hf = d_in[0];
    const void* c_lf = d_in[1];
    const void* s_hf = d_in[2];
    const void* s_lf = d_in[3];
    const void* kp_h_sp_w = d_in[4];
    const void* kp_h_sp_b = d_in[5];
    const void* kp_h_pw_w = d_in[6];
    const void* kp_h_pw_b = d_in[7];
    const void* kp_h_b_w = d_in[8];
    const void* kp_h_b_b = d_in[9];
    const void* kp_l_sp_w = d_in[10];
    const void* kp_l_sp_b = d_in[11];
    const void* kp_l_pw_w = d_in[12];
    const void* kp_l_pw_b = d_in[13];
    const void* kp_l_b_w = d_in[14];
    const void* kp_l_b_b = d_in[15];
    const void* conv_h_w = d_in[16];
    const void* conv_h_b = d_in[17];
    const void* conv_l_w = d_in[18];
    const void* conv_l_b = d_in[19];

    int* flag = (int*)d_ws;
    float* f = (float*)d_ws;
    float* sm_h = f + 64;
    float* sm_l = f + 2112;
    float* wsp_h = f + 4160;
    float* wsp_l = f + 13376;
    float* wpw_h = f + 22592;
    float* wpw_l = f + 23616;
    float* bias_h = f + 24640;
    float* bias_l = f + 25152;
    float* xstat_h = f + 25664;
    float* xstat_l = f + 26688;
    float* ystat_h = f + 27712;
    float* ystat_l = f + 28736;
    float* band = (float*)((char*)d_ws + 131072);  // 4*128*34*256 f32 = 17.8 MB

    const int HWH = 256 * 256, HWL = 128 * 128;
    const long long OFF_L = 33554432LL;             // element offset of ol in d_out
    const long long BSTR_L = 4LL * 128 * 34 * 128;  // lf band region stride (floats)

    detect_kernel<<<1, 256, 0, stream>>>(c_hf, flag);

    // predictors
    sm_kernel<<<8, 256, 0, stream>>>(flag, s_hf, sm_h);
    sm_kernel<<<8, 256, 0, stream>>>(flag, s_lf, sm_l);
    spconv_kernel<<<1024, 256, 0, stream>>>(flag, s_hf, kp_h_sp_w, kp_h_sp_b, wsp_h);
    spconv_kernel<<<1024, 256, 0, stream>>>(flag, s_lf, kp_l_sp_w, kp_l_sp_b, wsp_l);
    pwbias_kernel<<<6, 256, 0, stream>>>(flag, sm_h, kp_h_pw_w, kp_h_pw_b, kp_h_b_w, kp_h_b_b, wpw_h, bias_h);
    pwbias_kernel<<<6, 256, 0, stream>>>(flag, sm_l, kp_l_pw_w, kp_l_pw_b, kp_l_b_w, kp_l_b_b, wpw_l, bias_l);

    // input instance-norm stats
    stats_kernel<<<512, 256, 0, stream>>>(flag, c_hf, 0, xstat_h, HWH);
    stats_kernel<<<512, 256, 0, stream>>>(flag, c_lf, 0, xstat_l, HWL);

    // hf: 8 bands of 32 rows; bigconv tile kernel 512 blocks = 2/CU
    for (int r0 = 0; r0 < 256; r0 += 32) {
        grouped_band_kernel<<<4 * 64 * 34, 256, 0, stream>>>(flag, c_hf, xstat_h, wsp_h, wpw_h,
                                                             bias_h, band, 256, 256, r0);
        bigconv_tile_kernel<<<512, 256, 0, stream>>>(flag, band, conv_h_w, conv_h_b,
                                                     d_out, 0, 256, 256, r0, 1, 0);
    }
    // lf: 2 iterations, each with two 32-row bands resident -> 512-block bigconv
    for (int r0 = 0; r0 < 128; r0 += 64) {
        grouped_band_kernel<<<4 * 64 * 17, 256, 0, stream>>>(flag, c_lf, xstat_l, wsp_l, wpw_l,
                                                             bias_l, band, 128, 128, r0);
        grouped_band_kernel<<<4 * 64 * 17, 256, 0, stream>>>(flag, c_lf, xstat_l, wsp_l, wpw_l,
                                                             bias_l, band + BSTR_L, 128, 128, r0 + 32);
        bigconv_tile_kernel<<<512, 256, 0, stream>>>(flag, band, conv_l_w, conv_l_b,
                                                     d_out, OFF_L, 128, 128, r0, 2, BSTR_L);
    }

    // output instance-norm stats + finalize in place
    stats_kernel<<<512, 256, 0, stream>>>(flag, d_out, 0, ystat_h, HWH);
    stats_kernel<<<512, 256, 0, stream>>>(flag, d_out, OFF_L, ystat_l, HWL);
    finalize_kernel<<<131072, 256, 0, stream>>>(flag, d_out, 0, ystat_h, HWH, (long long)BB * CCH * HWH);
    finalize_kernel<<<32768, 256, 0, stream>>>(flag, d_out, OFF_L, ystat_l, HWL, (long long)BB * CCH * HWL);
}